// Round 13
// baseline (214.347 us; speedup 1.0000x reference)
//
#include <hip/hip_runtime.h>

#define DEV __device__ __forceinline__

// Hardware waits + compiler reorder fences. Each followed by sched_barrier(0)
// to stop the scheduler moving anything across the wait (rule #18 class).
#define LDS_FENCE() do { asm volatile("s_waitcnt lgkmcnt(0)" ::: "memory"); \
                         __builtin_amdgcn_sched_barrier(0); } while (0)
#define VM_FENCE()  do { asm volatile("s_waitcnt vmcnt(0)" ::: "memory");  \
                         __builtin_amdgcn_sched_barrier(0); } while (0)

typedef __fp16 h16x2 __attribute__((ext_vector_type(2)));

// Direct global->LDS DMA, 16B per lane. LDS dest = uniform base + lane*16,
// global src = per-lane address.
DEV void gload_lds16(const void* g, void* lds) {
    __builtin_amdgcn_global_load_lds(
        (const __attribute__((address_space(1))) void*)g,
        (__attribute__((address_space(3))) void*)lds,
        16, 0, 0);
}

// v_dot2_f32_f16: acc += a.x*b.x + a.y*b.y (fp16 mul, fp32 accumulate)
DEV float dot2(h16x2 a, h16x2 b, float acc) {
    asm("v_dot2_f32_f16 %0, %1, %2, %0" : "+v"(acc) : "v"(a), "v"(b));
    return acc;
}

DEV h16x2 f2h(float a, float b) { return __builtin_amdgcn_cvt_pkrtz(a, b); }

DEV float fast_sigmoid(float v) {
    return __builtin_amdgcn_rcpf(1.0f + __builtin_amdgcn_exp2f(-1.4426950408889634f * v));
}

// Per-sample math. Weights: k-pair-packed half2 in LDS (broadcast reads).
// sW1h: [16 i-pairs][16 j]  half2 ; sW2h: [8 j-pairs][32 c] half2.
DEV void compute_sample(const float (&p)[51], const float (&a)[17], const float (&g)[16],
                        const float4* sW1h4, const float4* sW2h4, float (&o)[51])
{
    constexpr int PAR[16] = {0,1,2,0,4,5,0,7,8,9,8,11,12,8,14,15};
    constexpr int CHI[16] = {1,2,3,4,5,6,7,8,9,10,11,12,13,14,15,16};

    float x[32], invn[16];
    #pragma unroll
    for (int k = 0; k < 16; ++k) {
        const int P = PAR[k] * 3, C = CHI[k] * 3;
        const float dx = p[P]   - p[C];
        const float dy = p[P+1] - p[C+1];
        const float dz = p[P+2] - p[C+2];
        const float n  = __builtin_amdgcn_sqrtf(fmaf(dx,dx, fmaf(dy,dy, dz*dz)));
        const float dis = g[k] - n;
        const float ap = a[PAR[k]], ac = a[CHI[k]];
        const float inv_asum = __builtin_amdgcn_rcpf(ap + ac + 1e-9f);
        x[2*k]   = dis * ac * inv_asum;
        x[2*k+1] = dis * ap * inv_asum;
        invn[k]  = __builtin_amdgcn_rcpf(n + 1e-9f);
    }

    // ---- pack x into k-pairs (half2) ----
    h16x2 xp[16];
    #pragma unroll
    for (int ip = 0; ip < 16; ++ip) xp[ip] = f2h(x[2*ip], x[2*ip+1]);

    // ---- layer 1: y[16] = relu(x @ W1), dot2 over k-pairs ----
    float y[16];
    #pragma unroll
    for (int j = 0; j < 16; ++j) y[j] = 0.f;
    #pragma unroll
    for (int ip = 0; ip < 16; ++ip) {
        #pragma unroll
        for (int jj = 0; jj < 4; ++jj) {
            const float4 wq = sW1h4[ip*4 + jj];      // 4 half2: j = 4jj..4jj+3
            y[4*jj+0] = dot2(xp[ip], __builtin_bit_cast(h16x2, wq.x), y[4*jj+0]);
            y[4*jj+1] = dot2(xp[ip], __builtin_bit_cast(h16x2, wq.y), y[4*jj+1]);
            y[4*jj+2] = dot2(xp[ip], __builtin_bit_cast(h16x2, wq.z), y[4*jj+2]);
            y[4*jj+3] = dot2(xp[ip], __builtin_bit_cast(h16x2, wq.w), y[4*jj+3]);
        }
    }
    h16x2 hp[8];
    #pragma unroll
    for (int jp = 0; jp < 8; ++jp)
        hp[jp] = f2h(fmaxf(y[2*jp], 0.f), fmaxf(y[2*jp+1], 0.f));

    // ---- layer 2: gate[32] = h @ W2, dot2 over j-pairs ----
    float gg[32];
    #pragma unroll
    for (int c = 0; c < 32; ++c) gg[c] = 0.f;
    #pragma unroll
    for (int jp = 0; jp < 8; ++jp) {
        #pragma unroll
        for (int cc = 0; cc < 8; ++cc) {
            const float4 wq = sW2h4[jp*8 + cc];      // 4 half2: c = 4cc..4cc+3
            gg[4*cc+0] = dot2(hp[jp], __builtin_bit_cast(h16x2, wq.x), gg[4*cc+0]);
            gg[4*cc+1] = dot2(hp[jp], __builtin_bit_cast(h16x2, wq.y), gg[4*cc+1]);
            gg[4*cc+2] = dot2(hp[jp], __builtin_bit_cast(h16x2, wq.z), gg[4*cc+2]);
            gg[4*cc+3] = dot2(hp[jp], __builtin_bit_cast(h16x2, wq.w), gg[4*cc+3]);
        }
    }

    float xg[32];
    #pragma unroll
    for (int c = 0; c < 32; ++c) xg[c] = x[c] * fast_sigmoid(gg[c]);
    #pragma unroll
    for (int k = 0; k < 16; ++k) {
        xg[2*k]   *= invn[k];
        xg[2*k+1] *= invn[k];
    }

    #pragma unroll
    for (int j = 0; j < 17; ++j) {
        float ox = p[3*j], oy = p[3*j+1], oz = p[3*j+2];
        #pragma unroll
        for (int k = 0; k < 16; ++k) {
            if (PAR[k] == j || CHI[k] == j) {   // compile-time after unroll
                const int P = PAR[k] * 3, C = CHI[k] * 3;
                const float dx = p[P]   - p[C];
                const float dy = p[P+1] - p[C+1];
                const float dz = p[P+2] - p[C+2];
                const float s = (PAR[k] == j) ? xg[2*k] : -xg[2*k+1];
                ox = fmaf(s, dx, ox);
                oy = fmaf(s, dy, oy);
                oz = fmaf(s, dz, oz);
            }
        }
        o[3*j]   = ox;
        o[3*j+1] = oy;
        o[3*j+2] = oz;
    }
}

__global__ __launch_bounds__(256, 3) void projts_kernel(
    const float* __restrict__ pred,
    const float* __restrict__ gt,
    const float* __restrict__ anc,
    const float* __restrict__ gW1,
    const float* __restrict__ gW2,
    float* __restrict__ out,
    int B)
{
    constexpr int ROW = 51;            // floats per sample in pred/out
    constexpr int WBUF = 64 * ROW;     // 3264 dwords = 13056 B per wave

    __shared__ h16x2 sW1h[256] __attribute__((aligned(16)));  // [16 ipair][16 j]
    __shared__ h16x2 sW2h[256] __attribute__((aligned(16)));  // [8 jpair][32 c]
    __shared__ float sbuf[4][WBUF] __attribute__((aligned(16)));  // pred/anc/out
    // total LDS: 52224 + 2048 = 54272 B -> 3 blocks/CU (12 waves/CU)

    const int t = threadIdx.x;

    // ---- one-time weight convert fp32 -> packed half2 (2 KB LDS) ----
    {
        const int ip = t >> 4, j = t & 15;
        sW1h[t] = f2h(gW1[32*ip + j], gW1[32*ip + 16 + j]);
        const int jp = t >> 5, c = t & 31;
        sW2h[t] = f2h(gW2[64*jp + c], gW2[64*jp + 32 + c]);
    }
    __syncthreads();

    const float4* sW1h4 = reinterpret_cast<const float4*>(sW1h);
    const float4* sW2h4 = reinterpret_cast<const float4*>(sW2h);

    const int w = t >> 6;
    const int l = t & 63;
    const long long wavebase = ((long long)blockIdx.x * 4 + w) * 64;
    if (wavebase >= B) return;

    float* buf  = sbuf[w];
    float4* buf4 = reinterpret_cast<float4*>(buf);

    if (wavebase + 64 <= (long long)B) {
        // ================= coalesced fast path (full wave) =================
        float p[51], a[17], o[51];

        const char* srcB = reinterpret_cast<const char*>(pred + (size_t)wavebase * ROW);
        char* bufB = reinterpret_cast<char*>(buf);

        // ---- pred: 816 float4 via global_load_lds (13 issues, last masked) ----
        #pragma unroll
        for (int i = 0; i < 12; ++i)
            gload_lds16(srcB + (size_t)(i*64 + l)*16, bufB + i*1024);
        if (l < 48)
            gload_lds16(srcB + (size_t)(768 + l)*16, bufB + 12*1024);

        // ---- anchors: coalesced float4 loads into REGISTERS (20 VGPR).
        //      NO divergence: tail load uses clamped lane index (in-bounds). ----
        const float4* asrc4 = reinterpret_cast<const float4*>(anc + (size_t)wavebase * 17);
        float4 ar0 = asrc4[0*64 + l];
        float4 ar1 = asrc4[1*64 + l];
        float4 ar2 = asrc4[2*64 + l];
        float4 ar3 = asrc4[3*64 + l];
        float4 ar4 = asrc4[256 + (l & 15)];   // lanes 16..63 duplicate lanes 0..15

        // ---- gt: 64B/sample, 16B aligned -> direct float4 reg loads ----
        const float4* gsrc4 = reinterpret_cast<const float4*>(gt + (size_t)(wavebase + l) * 16);
        const float4 gq0 = gsrc4[0], gq1 = gsrc4[1], gq2 = gsrc4[2], gq3 = gsrc4[3];

        VM_FENCE();    // pred DMA in LDS; anc/gt values in regs

        // ---- p readback: stride 51 (odd) -> bank-conflict-free ----
        #pragma unroll
        for (int j = 0; j < ROW; ++j) p[j] = buf[l*ROW + j];
        LDS_FENCE();   // p reads drained before anc overwrites pred region (WAR)

        // ---- write anc regs into freed pred buffer (all lanes, no branches).
        //      Lanes >=16 of the last write land in consumed pred floats
        //      1088..1343 -- harmless, overwritten by out-transpose later. ----
        buf4[0*64 + l] = ar0;
        buf4[1*64 + l] = ar1;
        buf4[2*64 + l] = ar2;
        buf4[3*64 + l] = ar3;
        buf4[256 + l]  = ar4;
        LDS_FENCE();

        #pragma unroll
        for (int j = 0; j < 17; ++j) a[j] = buf[l*17 + j];
        LDS_FENCE();   // a reads drained before out overwrites region (WAR)

        const float g[16] = {gq0.x,gq0.y,gq0.z,gq0.w, gq1.x,gq1.y,gq1.z,gq1.w,
                             gq2.x,gq2.y,gq2.z,gq2.w, gq3.x,gq3.y,gq3.z,gq3.w};

        compute_sample(p, a, g, sW1h4, sW2h4, o);

        // ---- transpose out through LDS (reuse buffer), coalesced stores ----
        #pragma unroll
        for (int j = 0; j < ROW; ++j) buf[l*ROW + j] = o[j];
        LDS_FENCE();

        float4* dst4 = reinterpret_cast<float4*>(out + (size_t)wavebase * ROW);
        #pragma unroll
        for (int i = 0; i < 12; ++i) dst4[i*64 + l] = buf4[i*64 + l];
        if (l < 48) dst4[768 + l] = buf4[768 + l];
    } else {
        // ================= scalar tail path (partial wave) =================
        const long long b = wavebase + l;
        if (b < B) {
            float p[51], a[17], g[16], o[51];
            const float* pj = pred + (size_t)b * 51;
            #pragma unroll
            for (int j = 0; j < 51; ++j) p[j] = pj[j];
            const float* ab = anc + (size_t)b * 17;
            #pragma unroll
            for (int j = 0; j < 17; ++j) a[j] = ab[j];
            const float* gb = gt + (size_t)b * 16;
            #pragma unroll
            for (int j = 0; j < 16; ++j) g[j] = gb[j];

            compute_sample(p, a, g, sW1h4, sW2h4, o);

            float* ob = out + (size_t)b * 51;
            #pragma unroll
            for (int j = 0; j < 51; ++j) ob[j] = o[j];
        }
    }
}

extern "C" void kernel_launch(void* const* d_in, const int* in_sizes, int n_in,
                              void* d_out, int out_size, void* d_ws, size_t ws_size,
                              hipStream_t stream) {
    const float* pred = (const float*)d_in[0];
    const float* gt   = (const float*)d_in[1];
    const float* anc  = (const float*)d_in[2];
    const float* W1   = (const float*)d_in[3];
    const float* W2   = (const float*)d_in[4];
    float* out = (float*)d_out;

    const int B = in_sizes[0] / 51;
    const int blocks = (B + 255) / 256;
    hipLaunchKernelGGL(projts_kernel, dim3(blocks), dim3(256), 0, stream,
                       pred, gt, anc, W1, W2, out, B);
}

// Round 15
// 113.354 us; speedup vs baseline: 1.8909x; 1.8909x over previous
//
#include <hip/hip_runtime.h>

#define DEV __device__ __forceinline__

typedef __fp16 h16x2 __attribute__((ext_vector_type(2)));

// Direct global->LDS DMA, 16B per lane. LDS dest = uniform base + lane*16,
// global src = per-lane address.
DEV void gload_lds16(const void* g, void* lds) {
    __builtin_amdgcn_global_load_lds(
        (const __attribute__((address_space(1))) void*)g,
        (__attribute__((address_space(3))) void*)lds,
        16, 0, 0);
}

// v_dot2_f32_f16: acc += a.x*b.x + a.y*b.y (fp16 mul, fp32 accumulate)
DEV float dot2(h16x2 a, h16x2 b, float acc) {
    asm("v_dot2_f32_f16 %0, %1, %2, %0" : "+v"(acc) : "v"(a), "v"(b));
    return acc;
}

DEV h16x2 f2h(float a, float b) { return __builtin_amdgcn_cvt_pkrtz(a, b); }

DEV float fast_sigmoid(float v) {
    return __builtin_amdgcn_rcpf(1.0f + __builtin_amdgcn_exp2f(-1.4426950408889634f * v));
}

// Per-sample math. Weights: k-pair-packed half2 in LDS (broadcast reads).
// sW1h: [16 i-pairs][16 j]  half2 ; sW2h: [8 j-pairs][32 c] half2.
DEV void compute_sample(const float (&p)[51], const float (&a)[17], const float (&g)[16],
                        const float4* sW1h4, const float4* sW2h4, float (&o)[51])
{
    constexpr int PAR[16] = {0,1,2,0,4,5,0,7,8,9,8,11,12,8,14,15};
    constexpr int CHI[16] = {1,2,3,4,5,6,7,8,9,10,11,12,13,14,15,16};

    float x[32], invn[16];
    #pragma unroll
    for (int k = 0; k < 16; ++k) {
        const int P = PAR[k] * 3, C = CHI[k] * 3;
        const float dx = p[P]   - p[C];
        const float dy = p[P+1] - p[C+1];
        const float dz = p[P+2] - p[C+2];
        const float n  = __builtin_amdgcn_sqrtf(fmaf(dx,dx, fmaf(dy,dy, dz*dz)));
        const float dis = g[k] - n;
        const float ap = a[PAR[k]], ac = a[CHI[k]];
        const float inv_asum = __builtin_amdgcn_rcpf(ap + ac + 1e-9f);
        x[2*k]   = dis * ac * inv_asum;
        x[2*k+1] = dis * ap * inv_asum;
        invn[k]  = __builtin_amdgcn_rcpf(n + 1e-9f);
    }

    // ---- pack x into k-pairs (half2) ----
    h16x2 xp[16];
    #pragma unroll
    for (int ip = 0; ip < 16; ++ip) xp[ip] = f2h(x[2*ip], x[2*ip+1]);

    // ---- layer 1: y[16] = relu(x @ W1), dot2 over k-pairs ----
    float y[16];
    #pragma unroll
    for (int j = 0; j < 16; ++j) y[j] = 0.f;
    #pragma unroll
    for (int ip = 0; ip < 16; ++ip) {
        #pragma unroll
        for (int jj = 0; jj < 4; ++jj) {
            const float4 wq = sW1h4[ip*4 + jj];      // 4 half2: j = 4jj..4jj+3
            y[4*jj+0] = dot2(xp[ip], __builtin_bit_cast(h16x2, wq.x), y[4*jj+0]);
            y[4*jj+1] = dot2(xp[ip], __builtin_bit_cast(h16x2, wq.y), y[4*jj+1]);
            y[4*jj+2] = dot2(xp[ip], __builtin_bit_cast(h16x2, wq.z), y[4*jj+2]);
            y[4*jj+3] = dot2(xp[ip], __builtin_bit_cast(h16x2, wq.w), y[4*jj+3]);
        }
    }
    h16x2 hp[8];
    #pragma unroll
    for (int jp = 0; jp < 8; ++jp)
        hp[jp] = f2h(fmaxf(y[2*jp], 0.f), fmaxf(y[2*jp+1], 0.f));

    // ---- layer 2: gate[32] = h @ W2, dot2 over j-pairs ----
    float gg[32];
    #pragma unroll
    for (int c = 0; c < 32; ++c) gg[c] = 0.f;
    #pragma unroll
    for (int jp = 0; jp < 8; ++jp) {
        #pragma unroll
        for (int cc = 0; cc < 8; ++cc) {
            const float4 wq = sW2h4[jp*8 + cc];      // 4 half2: c = 4cc..4cc+3
            gg[4*cc+0] = dot2(hp[jp], __builtin_bit_cast(h16x2, wq.x), gg[4*cc+0]);
            gg[4*cc+1] = dot2(hp[jp], __builtin_bit_cast(h16x2, wq.y), gg[4*cc+1]);
            gg[4*cc+2] = dot2(hp[jp], __builtin_bit_cast(h16x2, wq.z), gg[4*cc+2]);
            gg[4*cc+3] = dot2(hp[jp], __builtin_bit_cast(h16x2, wq.w), gg[4*cc+3]);
        }
    }

    float xg[32];
    #pragma unroll
    for (int c = 0; c < 32; ++c) xg[c] = x[c] * fast_sigmoid(gg[c]);
    #pragma unroll
    for (int k = 0; k < 16; ++k) {
        xg[2*k]   *= invn[k];
        xg[2*k+1] *= invn[k];
    }

    #pragma unroll
    for (int j = 0; j < 17; ++j) {
        float ox = p[3*j], oy = p[3*j+1], oz = p[3*j+2];
        #pragma unroll
        for (int k = 0; k < 16; ++k) {
            if (PAR[k] == j || CHI[k] == j) {   // compile-time after unroll
                const int P = PAR[k] * 3, C = CHI[k] * 3;
                const float dx = p[P]   - p[C];
                const float dy = p[P+1] - p[C+1];
                const float dz = p[P+2] - p[C+2];
                const float s = (PAR[k] == j) ? xg[2*k] : -xg[2*k+1];
                ox = fmaf(s, dx, ox);
                oy = fmaf(s, dy, oy);
                oz = fmaf(s, dz, oz);
            }
        }
        o[3*j]   = ox;
        o[3*j+1] = oy;
        o[3*j+2] = oz;
    }
}

__global__ __launch_bounds__(256, 2) void projts_kernel(
    const float* __restrict__ pred,
    const float* __restrict__ gt,
    const float* __restrict__ anc,
    const float* __restrict__ gW1,
    const float* __restrict__ gW2,
    float* __restrict__ out,
    int B)
{
    constexpr int ROW = 51;            // floats per sample in pred/out
    constexpr int WBUF = 64 * ROW;     // 3264 dwords = 13056 B per wave

    __shared__ h16x2 sW1h[256] __attribute__((aligned(16)));  // [16 ipair][16 j]
    __shared__ h16x2 sW2h[256] __attribute__((aligned(16)));  // [8 jpair][32 c]
    __shared__ float sbuf[4][WBUF] __attribute__((aligned(16)));  // pred/anc/out
    // total LDS: 52224 + 2048 = 54272 B -> 3 blocks/CU at ~128-170 VGPR

    const int t = threadIdx.x;

    // ---- one-time weight convert fp32 -> packed half2 (2 KB LDS) ----
    {
        const int ip = t >> 4, j = t & 15;
        sW1h[t] = f2h(gW1[32*ip + j], gW1[32*ip + 16 + j]);
        const int jp = t >> 5, c = t & 31;
        sW2h[t] = f2h(gW2[64*jp + c], gW2[64*jp + 32 + c]);
    }
    __syncthreads();

    const float4* sW1h4 = reinterpret_cast<const float4*>(sW1h);
    const float4* sW2h4 = reinterpret_cast<const float4*>(sW2h);

    const int w = t >> 6;
    const int l = t & 63;

    // Block-uniform path choice so __syncthreads participation is uniform.
    if ((long long)(blockIdx.x + 1) * 256 <= (long long)B) {
        // ================= coalesced fast path (full block) =================
        const long long wavebase = ((long long)blockIdx.x * 4 + w) * 64;
        float* buf  = sbuf[w];
        float4* buf4 = reinterpret_cast<float4*>(buf);
        float p[51], a[17], o[51];

        const char* srcB = reinterpret_cast<const char*>(pred + (size_t)wavebase * ROW);
        char* bufB = reinterpret_cast<char*>(buf);

        // ---- phase 1: issue all global traffic ----
        #pragma unroll
        for (int i = 0; i < 12; ++i)
            gload_lds16(srcB + (size_t)(i*64 + l)*16, bufB + i*1024);
        if (l < 48)
            gload_lds16(srcB + (size_t)(768 + l)*16, bufB + 12*1024);

        const float4* asrc4 = reinterpret_cast<const float4*>(anc + (size_t)wavebase * 17);
        float4 ar0 = asrc4[0*64 + l];
        float4 ar1 = asrc4[1*64 + l];
        float4 ar2 = asrc4[2*64 + l];
        float4 ar3 = asrc4[3*64 + l];
        float4 ar4 = asrc4[256 + (l & 15)];   // lanes 16..63 duplicate 0..15

        const float4* gsrc4 = reinterpret_cast<const float4*>(gt + (size_t)(wavebase + l) * 16);
        const float4 gq0 = gsrc4[0], gq1 = gsrc4[1], gq2 = gsrc4[2], gq3 = gsrc4[3];

        __syncthreads();   // drains vmcnt(0): DMA in LDS, anc/gt in regs

        // ---- phase 2: p readback (stride 51, odd -> conflict-free) ----
        #pragma unroll
        for (int j = 0; j < ROW; ++j) p[j] = buf[l*ROW + j];

        __syncthreads();   // p reads drained before anc overwrites region (WAR)

        // ---- phase 3: write anc regs into freed pred buffer (no branches).
        //      Lanes >=16 of the last write land in consumed pred floats
        //      1088..1279 -- already read into p, overwritten later. ----
        buf4[0*64 + l] = ar0;
        buf4[1*64 + l] = ar1;
        buf4[2*64 + l] = ar2;
        buf4[3*64 + l] = ar3;
        buf4[256 + l]  = ar4;

        __syncthreads();   // anc writes visible

        // ---- phase 4: a readback (stride 17, odd -> conflict-free) ----
        #pragma unroll
        for (int j = 0; j < 17; ++j) a[j] = buf[l*17 + j];

        __syncthreads();   // a reads drained before out overwrites region (WAR)

        const float g[16] = {gq0.x,gq0.y,gq0.z,gq0.w, gq1.x,gq1.y,gq1.z,gq1.w,
                             gq2.x,gq2.y,gq2.z,gq2.w, gq3.x,gq3.y,gq3.z,gq3.w};

        compute_sample(p, a, g, sW1h4, sW2h4, o);

        // ---- phase 5: transpose out through LDS, coalesced stores ----
        #pragma unroll
        for (int j = 0; j < ROW; ++j) buf[l*ROW + j] = o[j];

        __syncthreads();   // out writes visible

        float4* dst4 = reinterpret_cast<float4*>(out + (size_t)wavebase * ROW);
        #pragma unroll
        for (int i = 0; i < 12; ++i) dst4[i*64 + l] = buf4[i*64 + l];
        if (l < 48) dst4[768 + l] = buf4[768 + l];
    } else {
        // ============ scalar tail path (single partial block, no barriers) ============
        const long long b = (long long)blockIdx.x * 256 + t;
        if (b < B) {
            float p[51], a[17], g[16], o[51];
            const float* pj = pred + (size_t)b * 51;
            #pragma unroll
            for (int j = 0; j < 51; ++j) p[j] = pj[j];
            const float* ab = anc + (size_t)b * 17;
            #pragma unroll
            for (int j = 0; j < 17; ++j) a[j] = ab[j];
            const float* gb = gt + (size_t)b * 16;
            #pragma unroll
            for (int j = 0; j < 16; ++j) g[j] = gb[j];

            compute_sample(p, a, g, sW1h4, sW2h4, o);

            float* ob = out + (size_t)b * 51;
            #pragma unroll
            for (int j = 0; j < 51; ++j) ob[j] = o[j];
        }
    }
}

extern "C" void kernel_launch(void* const* d_in, const int* in_sizes, int n_in,
                              void* d_out, int out_size, void* d_ws, size_t ws_size,
                              hipStream_t stream) {
    const float* pred = (const float*)d_in[0];
    const float* gt   = (const float*)d_in[1];
    const float* anc  = (const float*)d_in[2];
    const float* W1   = (const float*)d_in[3];
    const float* W2   = (const float*)d_in[4];
    float* out = (float*)d_out;

    const int B = in_sizes[0] / 51;
    const int blocks = (B + 255) / 256;
    hipLaunchKernelGGL(projts_kernel, dim3(blocks), dim3(256), 0, stream,
                       pred, gt, anc, W1, W2, out, B);
}

// Round 17
// 107.605 us; speedup vs baseline: 1.9920x; 1.0534x over previous
//
#include <hip/hip_runtime.h>

#define DEV __device__ __forceinline__

typedef __fp16 h16x2 __attribute__((ext_vector_type(2)));

// Direct global->LDS DMA, 16B per lane. LDS dest = uniform base + lane*16,
// global src = per-lane address.
DEV void gload_lds16(const void* g, void* lds) {
    __builtin_amdgcn_global_load_lds(
        (const __attribute__((address_space(1))) void*)g,
        (__attribute__((address_space(3))) void*)lds,
        16, 0, 0);
}

// v_dot2_f32_f16: acc += a.x*b.x + a.y*b.y (fp16 mul, fp32 accumulate)
DEV float dot2(h16x2 a, h16x2 b, float acc) {
    asm("v_dot2_f32_f16 %0, %1, %2, %0" : "+v"(acc) : "v"(a), "v"(b));
    return acc;
}

DEV h16x2 f2h(float a, float b) { return __builtin_amdgcn_cvt_pkrtz(a, b); }

DEV float fast_sigmoid(float v) {
    return __builtin_amdgcn_rcpf(1.0f + __builtin_amdgcn_exp2f(-1.4426950408889634f * v));
}

// Skeleton tables.
#define SKEL_TABLES \
    constexpr int PAR[16] = {0,1,2,0,4,5,0,7,8,9,8,11,12,8,14,15}; \
    constexpr int CHI[16] = {1,2,3,4,5,6,7,8,9,10,11,12,13,14,15,16};

// Fast-path per-sample math. Weights: k-pair-packed half2 read from this
// wave's sbuf tail (broadcast ds reads).
DEV void compute_sample(const float (&p)[51], const float (&a)[17], const float (&g)[16],
                        const float4* sW1h4, const float4* sW2h4, float (&o)[51])
{
    SKEL_TABLES

    float x[32], invn[16];
    #pragma unroll
    for (int k = 0; k < 16; ++k) {
        const int P = PAR[k] * 3, C = CHI[k] * 3;
        const float dx = p[P]   - p[C];
        const float dy = p[P+1] - p[C+1];
        const float dz = p[P+2] - p[C+2];
        const float n  = __builtin_amdgcn_sqrtf(fmaf(dx,dx, fmaf(dy,dy, dz*dz)));
        const float dis = g[k] - n;
        const float ap = a[PAR[k]], ac = a[CHI[k]];
        const float inv_asum = __builtin_amdgcn_rcpf(ap + ac + 1e-9f);
        x[2*k]   = dis * ac * inv_asum;
        x[2*k+1] = dis * ap * inv_asum;
        invn[k]  = __builtin_amdgcn_rcpf(n + 1e-9f);
    }

    h16x2 xp[16];
    #pragma unroll
    for (int ip = 0; ip < 16; ++ip) xp[ip] = f2h(x[2*ip], x[2*ip+1]);

    float y[16];
    #pragma unroll
    for (int j = 0; j < 16; ++j) y[j] = 0.f;
    #pragma unroll
    for (int ip = 0; ip < 16; ++ip) {
        #pragma unroll
        for (int jj = 0; jj < 4; ++jj) {
            const float4 wq = sW1h4[ip*4 + jj];      // 4 half2: j = 4jj..4jj+3
            y[4*jj+0] = dot2(xp[ip], __builtin_bit_cast(h16x2, wq.x), y[4*jj+0]);
            y[4*jj+1] = dot2(xp[ip], __builtin_bit_cast(h16x2, wq.y), y[4*jj+1]);
            y[4*jj+2] = dot2(xp[ip], __builtin_bit_cast(h16x2, wq.z), y[4*jj+2]);
            y[4*jj+3] = dot2(xp[ip], __builtin_bit_cast(h16x2, wq.w), y[4*jj+3]);
        }
    }
    h16x2 hp[8];
    #pragma unroll
    for (int jp = 0; jp < 8; ++jp)
        hp[jp] = f2h(fmaxf(y[2*jp], 0.f), fmaxf(y[2*jp+1], 0.f));

    float gg[32];
    #pragma unroll
    for (int c = 0; c < 32; ++c) gg[c] = 0.f;
    #pragma unroll
    for (int jp = 0; jp < 8; ++jp) {
        #pragma unroll
        for (int cc = 0; cc < 8; ++cc) {
            const float4 wq = sW2h4[jp*8 + cc];      // 4 half2: c = 4cc..4cc+3
            gg[4*cc+0] = dot2(hp[jp], __builtin_bit_cast(h16x2, wq.x), gg[4*cc+0]);
            gg[4*cc+1] = dot2(hp[jp], __builtin_bit_cast(h16x2, wq.y), gg[4*cc+1]);
            gg[4*cc+2] = dot2(hp[jp], __builtin_bit_cast(h16x2, wq.z), gg[4*cc+2]);
            gg[4*cc+3] = dot2(hp[jp], __builtin_bit_cast(h16x2, wq.w), gg[4*cc+3]);
        }
    }

    float xg[32];
    #pragma unroll
    for (int c = 0; c < 32; ++c) xg[c] = x[c] * fast_sigmoid(gg[c]);
    #pragma unroll
    for (int k = 0; k < 16; ++k) {
        xg[2*k]   *= invn[k];
        xg[2*k+1] *= invn[k];
    }

    #pragma unroll
    for (int j = 0; j < 17; ++j) {
        float ox = p[3*j], oy = p[3*j+1], oz = p[3*j+2];
        #pragma unroll
        for (int k = 0; k < 16; ++k) {
            if (PAR[k] == j || CHI[k] == j) {   // compile-time after unroll
                const int P = PAR[k] * 3, C = CHI[k] * 3;
                const float dx = p[P]   - p[C];
                const float dy = p[P+1] - p[C+1];
                const float dz = p[P+2] - p[C+2];
                const float s = (PAR[k] == j) ? xg[2*k] : -xg[2*k+1];
                ox = fmaf(s, dx, ox);
                oy = fmaf(s, dy, oy);
                oz = fmaf(s, dz, oz);
            }
        }
        o[3*j]   = ox;
        o[3*j+1] = oy;
        o[3*j+2] = oz;
    }
}

// Tail-path per-sample math: fp32 weights straight from global (64 samples,
// perf-irrelevant).
DEV void compute_sample_f32(const float (&p)[51], const float (&a)[17], const float (&g)[16],
                            const float* __restrict__ gW1, const float* __restrict__ gW2,
                            float (&o)[51])
{
    SKEL_TABLES

    float x[32], invn[16];
    #pragma unroll
    for (int k = 0; k < 16; ++k) {
        const int P = PAR[k] * 3, C = CHI[k] * 3;
        const float dx = p[P]   - p[C];
        const float dy = p[P+1] - p[C+1];
        const float dz = p[P+2] - p[C+2];
        const float n  = __builtin_amdgcn_sqrtf(fmaf(dx,dx, fmaf(dy,dy, dz*dz)));
        const float dis = g[k] - n;
        const float ap = a[PAR[k]], ac = a[CHI[k]];
        const float inv_asum = __builtin_amdgcn_rcpf(ap + ac + 1e-9f);
        x[2*k]   = dis * ac * inv_asum;
        x[2*k+1] = dis * ap * inv_asum;
        invn[k]  = __builtin_amdgcn_rcpf(n + 1e-9f);
    }

    float y[16];
    #pragma unroll
    for (int j = 0; j < 16; ++j) y[j] = 0.f;
    for (int i = 0; i < 32; ++i) {
        const float xi = x[i];
        #pragma unroll
        for (int j = 0; j < 16; ++j) y[j] = fmaf(xi, gW1[i*16 + j], y[j]);
    }
    float h[16];
    #pragma unroll
    for (int j = 0; j < 16; ++j) h[j] = fmaxf(y[j], 0.f);

    float gg[32];
    #pragma unroll
    for (int c = 0; c < 32; ++c) gg[c] = 0.f;
    for (int j = 0; j < 16; ++j) {
        const float hj = h[j];
        #pragma unroll
        for (int c = 0; c < 32; ++c) gg[c] = fmaf(hj, gW2[j*32 + c], gg[c]);
    }

    float xg[32];
    #pragma unroll
    for (int c = 0; c < 32; ++c) xg[c] = x[c] * fast_sigmoid(gg[c]);
    #pragma unroll
    for (int k = 0; k < 16; ++k) {
        xg[2*k]   *= invn[k];
        xg[2*k+1] *= invn[k];
    }

    #pragma unroll
    for (int j = 0; j < 17; ++j) {
        float ox = p[3*j], oy = p[3*j+1], oz = p[3*j+2];
        #pragma unroll
        for (int k = 0; k < 16; ++k) {
            if (PAR[k] == j || CHI[k] == j) {
                const int P = PAR[k] * 3, C = CHI[k] * 3;
                const float dx = p[P]   - p[C];
                const float dy = p[P+1] - p[C+1];
                const float dz = p[P+2] - p[C+2];
                const float s = (PAR[k] == j) ? xg[2*k] : -xg[2*k+1];
                ox = fmaf(s, dx, ox);
                oy = fmaf(s, dy, oy);
                oz = fmaf(s, dz, oz);
            }
        }
        o[3*j]   = ox;
        o[3*j+1] = oy;
        o[3*j+2] = oz;
    }
}

__global__ __launch_bounds__(256, 2) void projts_kernel(
    const float* __restrict__ pred,
    const float* __restrict__ gt,
    const float* __restrict__ anc,
    const float* __restrict__ gW1,
    const float* __restrict__ gW2,
    float* __restrict__ out,
    int B)
{
    constexpr int ROW = 51;            // floats per sample in pred/out
    constexpr int WBUF = 64 * ROW;     // 3264 dwords = 13056 B per wave
    constexpr int WOFF1 = 1536;        // dword offset of packed W1 in sbuf tail
    constexpr int WOFF2 = 1792;        // dword offset of packed W2

    // ONLY LDS: 4 wave-private buffers. 52224 B -> 3 blocks/CU.
    __shared__ float sbuf[4][WBUF] __attribute__((aligned(16)));

    const int t = threadIdx.x;
    const int w = t >> 6;
    const int l = t & 63;

    float* buf  = sbuf[w];
    float4* buf4 = reinterpret_cast<float4*>(buf);

    // Block-uniform path choice so __syncthreads participation is uniform.
    if ((long long)(blockIdx.x + 1) * 256 <= (long long)B) {
        // ================= coalesced fast path (full block) =================
        const long long wavebase = ((long long)blockIdx.x * 4 + w) * 64;
        float p[51], a[17], o[51];

        const char* srcB = reinterpret_cast<const char*>(pred + (size_t)wavebase * ROW);
        char* bufB = reinterpret_cast<char*>(buf);

        // ---- phase 1: issue all global traffic ----
        #pragma unroll
        for (int i = 0; i < 12; ++i)
            gload_lds16(srcB + (size_t)(i*64 + l)*16, bufB + i*1024);
        if (l < 48)
            gload_lds16(srcB + (size_t)(768 + l)*16, bufB + 12*1024);

        const float4* asrc4 = reinterpret_cast<const float4*>(anc + (size_t)wavebase * 17);
        float4 ar0 = asrc4[0*64 + l];
        float4 ar1 = asrc4[1*64 + l];
        float4 ar2 = asrc4[2*64 + l];
        float4 ar3 = asrc4[3*64 + l];
        float4 ar4 = asrc4[256 + (l & 15)];   // lanes 16..63 duplicate 0..15

        const float4* gsrc4 = reinterpret_cast<const float4*>(gt + (size_t)(wavebase + l) * 16);
        const float4 gq0 = gsrc4[0], gq1 = gsrc4[1], gq2 = gsrc4[2], gq3 = gsrc4[3];

        // weight fragments for this lane's 8 packed entries (L1-hot)
        float w1a[4], w1b[4], w2a[4], w2b[4];
        #pragma unroll
        for (int q = 0; q < 4; ++q) {
            const int t4 = l + 64*q;
            const int ip = t4 >> 4, j = t4 & 15;
            w1a[q] = gW1[32*ip + j];
            w1b[q] = gW1[32*ip + 16 + j];
            const int jp = t4 >> 5, c = t4 & 31;
            w2a[q] = gW2[64*jp + c];
            w2b[q] = gW2[64*jp + 32 + c];
        }

        __syncthreads();   // drains vmcnt(0): DMA in LDS, anc/gt/weights in regs

        // ---- phase 2: p readback (stride 51, odd -> conflict-free) ----
        #pragma unroll
        for (int j = 0; j < ROW; ++j) p[j] = buf[l*ROW + j];

        __syncthreads();   // p reads drained before region reuse (WAR)

        // ---- phase 3: write anchors [0..1279] + packed weights [1536..2047]
        //      into this wave's freed buffer (no divergence). ----
        buf4[0*64 + l] = ar0;
        buf4[1*64 + l] = ar1;
        buf4[2*64 + l] = ar2;
        buf4[3*64 + l] = ar3;
        buf4[256 + l]  = ar4;
        #pragma unroll
        for (int q = 0; q < 4; ++q) {
            buf[WOFF1 + l + 64*q] = __builtin_bit_cast(float, f2h(w1a[q], w1b[q]));
            buf[WOFF2 + l + 64*q] = __builtin_bit_cast(float, f2h(w2a[q], w2b[q]));
        }

        __syncthreads();   // anc + weight writes visible

        // ---- phase 4: a readback (stride 17, odd -> conflict-free) ----
        #pragma unroll
        for (int j = 0; j < 17; ++j) a[j] = buf[l*17 + j];

        __syncthreads();   // a reads drained before out overwrites region (WAR)

        const float g[16] = {gq0.x,gq0.y,gq0.z,gq0.w, gq1.x,gq1.y,gq1.z,gq1.w,
                             gq2.x,gq2.y,gq2.z,gq2.w, gq3.x,gq3.y,gq3.z,gq3.w};

        const float4* sW1h4 = reinterpret_cast<const float4*>(buf + WOFF1);
        const float4* sW2h4 = reinterpret_cast<const float4*>(buf + WOFF2);
        compute_sample(p, a, g, sW1h4, sW2h4, o);

        // ---- phase 5: transpose out through LDS, coalesced stores ----
        #pragma unroll
        for (int j = 0; j < ROW; ++j) buf[l*ROW + j] = o[j];

        __syncthreads();   // out writes visible (also orders past weight reads)

        float4* dst4 = reinterpret_cast<float4*>(out + (size_t)wavebase * ROW);
        #pragma unroll
        for (int i = 0; i < 12; ++i) dst4[i*64 + l] = buf4[i*64 + l];
        if (l < 48) dst4[768 + l] = buf4[768 + l];
    } else {
        // ===== scalar tail path (single partial block, fp32 weights) =====
        const long long b = (long long)blockIdx.x * 256 + t;
        if (b < B) {
            float p[51], a[17], g[16], o[51];
            const float* pj = pred + (size_t)b * 51;
            #pragma unroll
            for (int j = 0; j < 51; ++j) p[j] = pj[j];
            const float* ab = anc + (size_t)b * 17;
            #pragma unroll
            for (int j = 0; j < 17; ++j) a[j] = ab[j];
            const float* gb = gt + (size_t)b * 16;
            #pragma unroll
            for (int j = 0; j < 16; ++j) g[j] = gb[j];

            compute_sample_f32(p, a, g, gW1, gW2, o);

            float* ob = out + (size_t)b * 51;
            #pragma unroll
            for (int j = 0; j < 51; ++j) ob[j] = o[j];
        }
    }
}

extern "C" void kernel_launch(void* const* d_in, const int* in_sizes, int n_in,
                              void* d_out, int out_size, void* d_ws, size_t ws_size,
                              hipStream_t stream) {
    const float* pred = (const float*)d_in[0];
    const float* gt   = (const float*)d_in[1];
    const float* anc  = (const float*)d_in[2];
    const float* W1   = (const float*)d_in[3];
    const float* W2   = (const float*)d_in[4];
    float* out = (float*)d_out;

    const int B = in_sizes[0] / 51;
    const int blocks = (B + 255) / 256;
    hipLaunchKernelGGL(projts_kernel, dim3(blocks), dim3(256), 0, stream,
                       pred, gt, anc, W1, W2, out, B);
}

// Round 18
// 102.963 us; speedup vs baseline: 2.0818x; 1.0451x over previous
//
#include <hip/hip_runtime.h>

#define DEV __device__ __forceinline__

typedef __fp16 h16x2 __attribute__((ext_vector_type(2)));

// Direct global->LDS DMA, 16B per lane. LDS dest = uniform base + lane*16,
// global src = per-lane address.
DEV void gload_lds16(const void* g, void* lds) {
    __builtin_amdgcn_global_load_lds(
        (const __attribute__((address_space(1))) void*)g,
        (__attribute__((address_space(3))) void*)lds,
        16, 0, 0);
}

// v_dot2_f32_f16: acc += a.x*b.x + a.y*b.y (fp16 mul, fp32 accumulate)
DEV float dot2(h16x2 a, h16x2 b, float acc) {
    asm("v_dot2_f32_f16 %0, %1, %2, %0" : "+v"(acc) : "v"(a), "v"(b));
    return acc;
}

DEV h16x2 f2h(float a, float b) { return __builtin_amdgcn_cvt_pkrtz(a, b); }

DEV float fast_sigmoid(float v) {
    return __builtin_amdgcn_rcpf(1.0f + __builtin_amdgcn_exp2f(-1.4426950408889634f * v));
}

// Skeleton tables.
#define SKEL_TABLES \
    constexpr int PAR[16] = {0,1,2,0,4,5,0,7,8,9,8,11,12,8,14,15}; \
    constexpr int CHI[16] = {1,2,3,4,5,6,7,8,9,10,11,12,13,14,15,16};

// Fast-path per-sample math. Weights: k-pair-packed half2 read from this
// wave's sbuf tail (broadcast ds reads).
DEV void compute_sample(const float (&p)[51], const float (&a)[17], const float (&g)[16],
                        const float4* sW1h4, const float4* sW2h4, float (&o)[51])
{
    SKEL_TABLES

    float x[32], invn[16];
    #pragma unroll
    for (int k = 0; k < 16; ++k) {
        const int P = PAR[k] * 3, C = CHI[k] * 3;
        const float dx = p[P]   - p[C];
        const float dy = p[P+1] - p[C+1];
        const float dz = p[P+2] - p[C+2];
        const float n  = __builtin_amdgcn_sqrtf(fmaf(dx,dx, fmaf(dy,dy, dz*dz)));
        const float dis = g[k] - n;
        const float ap = a[PAR[k]], ac = a[CHI[k]];
        const float inv_asum = __builtin_amdgcn_rcpf(ap + ac + 1e-9f);
        x[2*k]   = dis * ac * inv_asum;
        x[2*k+1] = dis * ap * inv_asum;
        invn[k]  = __builtin_amdgcn_rcpf(n + 1e-9f);
    }

    h16x2 xp[16];
    #pragma unroll
    for (int ip = 0; ip < 16; ++ip) xp[ip] = f2h(x[2*ip], x[2*ip+1]);

    float y[16];
    #pragma unroll
    for (int j = 0; j < 16; ++j) y[j] = 0.f;
    #pragma unroll
    for (int ip = 0; ip < 16; ++ip) {
        #pragma unroll
        for (int jj = 0; jj < 4; ++jj) {
            const float4 wq = sW1h4[ip*4 + jj];      // 4 half2: j = 4jj..4jj+3
            y[4*jj+0] = dot2(xp[ip], __builtin_bit_cast(h16x2, wq.x), y[4*jj+0]);
            y[4*jj+1] = dot2(xp[ip], __builtin_bit_cast(h16x2, wq.y), y[4*jj+1]);
            y[4*jj+2] = dot2(xp[ip], __builtin_bit_cast(h16x2, wq.z), y[4*jj+2]);
            y[4*jj+3] = dot2(xp[ip], __builtin_bit_cast(h16x2, wq.w), y[4*jj+3]);
        }
    }
    h16x2 hp[8];
    #pragma unroll
    for (int jp = 0; jp < 8; ++jp)
        hp[jp] = f2h(fmaxf(y[2*jp], 0.f), fmaxf(y[2*jp+1], 0.f));

    float gg[32];
    #pragma unroll
    for (int c = 0; c < 32; ++c) gg[c] = 0.f;
    #pragma unroll
    for (int jp = 0; jp < 8; ++jp) {
        #pragma unroll
        for (int cc = 0; cc < 8; ++cc) {
            const float4 wq = sW2h4[jp*8 + cc];      // 4 half2: c = 4cc..4cc+3
            gg[4*cc+0] = dot2(hp[jp], __builtin_bit_cast(h16x2, wq.x), gg[4*cc+0]);
            gg[4*cc+1] = dot2(hp[jp], __builtin_bit_cast(h16x2, wq.y), gg[4*cc+1]);
            gg[4*cc+2] = dot2(hp[jp], __builtin_bit_cast(h16x2, wq.z), gg[4*cc+2]);
            gg[4*cc+3] = dot2(hp[jp], __builtin_bit_cast(h16x2, wq.w), gg[4*cc+3]);
        }
    }

    float xg[32];
    #pragma unroll
    for (int c = 0; c < 32; ++c) xg[c] = x[c] * fast_sigmoid(gg[c]);
    #pragma unroll
    for (int k = 0; k < 16; ++k) {
        xg[2*k]   *= invn[k];
        xg[2*k+1] *= invn[k];
    }

    #pragma unroll
    for (int j = 0; j < 17; ++j) {
        float ox = p[3*j], oy = p[3*j+1], oz = p[3*j+2];
        #pragma unroll
        for (int k = 0; k < 16; ++k) {
            if (PAR[k] == j || CHI[k] == j) {   // compile-time after unroll
                const int P = PAR[k] * 3, C = CHI[k] * 3;
                const float dx = p[P]   - p[C];
                const float dy = p[P+1] - p[C+1];
                const float dz = p[P+2] - p[C+2];
                const float s = (PAR[k] == j) ? xg[2*k] : -xg[2*k+1];
                ox = fmaf(s, dx, ox);
                oy = fmaf(s, dy, oy);
                oz = fmaf(s, dz, oz);
            }
        }
        o[3*j]   = ox;
        o[3*j+1] = oy;
        o[3*j+2] = oz;
    }
}

// Tail-path per-sample math: fp32 weights straight from global (<=63 samples,
// perf-irrelevant).
DEV void compute_sample_f32(const float (&p)[51], const float (&a)[17], const float (&g)[16],
                            const float* __restrict__ gW1, const float* __restrict__ gW2,
                            float (&o)[51])
{
    SKEL_TABLES

    float x[32], invn[16];
    #pragma unroll
    for (int k = 0; k < 16; ++k) {
        const int P = PAR[k] * 3, C = CHI[k] * 3;
        const float dx = p[P]   - p[C];
        const float dy = p[P+1] - p[C+1];
        const float dz = p[P+2] - p[C+2];
        const float n  = __builtin_amdgcn_sqrtf(fmaf(dx,dx, fmaf(dy,dy, dz*dz)));
        const float dis = g[k] - n;
        const float ap = a[PAR[k]], ac = a[CHI[k]];
        const float inv_asum = __builtin_amdgcn_rcpf(ap + ac + 1e-9f);
        x[2*k]   = dis * ac * inv_asum;
        x[2*k+1] = dis * ap * inv_asum;
        invn[k]  = __builtin_amdgcn_rcpf(n + 1e-9f);
    }

    float y[16];
    #pragma unroll
    for (int j = 0; j < 16; ++j) y[j] = 0.f;
    for (int i = 0; i < 32; ++i) {
        const float xi = x[i];
        #pragma unroll
        for (int j = 0; j < 16; ++j) y[j] = fmaf(xi, gW1[i*16 + j], y[j]);
    }
    float h[16];
    #pragma unroll
    for (int j = 0; j < 16; ++j) h[j] = fmaxf(y[j], 0.f);

    float gg[32];
    #pragma unroll
    for (int c = 0; c < 32; ++c) gg[c] = 0.f;
    for (int j = 0; j < 16; ++j) {
        const float hj = h[j];
        #pragma unroll
        for (int c = 0; c < 32; ++c) gg[c] = fmaf(hj, gW2[j*32 + c], gg[c]);
    }

    float xg[32];
    #pragma unroll
    for (int c = 0; c < 32; ++c) xg[c] = x[c] * fast_sigmoid(gg[c]);
    #pragma unroll
    for (int k = 0; k < 16; ++k) {
        xg[2*k]   *= invn[k];
        xg[2*k+1] *= invn[k];
    }

    #pragma unroll
    for (int j = 0; j < 17; ++j) {
        float ox = p[3*j], oy = p[3*j+1], oz = p[3*j+2];
        #pragma unroll
        for (int k = 0; k < 16; ++k) {
            if (PAR[k] == j || CHI[k] == j) {
                const int P = PAR[k] * 3, C = CHI[k] * 3;
                const float dx = p[P]   - p[C];
                const float dy = p[P+1] - p[C+1];
                const float dz = p[P+2] - p[C+2];
                const float s = (PAR[k] == j) ? xg[2*k] : -xg[2*k+1];
                ox = fmaf(s, dx, ox);
                oy = fmaf(s, dy, oy);
                oz = fmaf(s, dz, oz);
            }
        }
        o[3*j]   = ox;
        o[3*j+1] = oy;
        o[3*j+2] = oz;
    }
}

// One wave (64 threads) per block. LDS = one 13,056 B staging buffer that is
// successively pred -> (anchors + packed weights) -> out. 10-12 blocks/CU.
__global__ __launch_bounds__(64, 2) void projts_kernel(
    const float* __restrict__ pred,
    const float* __restrict__ gt,
    const float* __restrict__ anc,
    const float* __restrict__ gW1,
    const float* __restrict__ gW2,
    float* __restrict__ out,
    int B)
{
    constexpr int ROW = 51;            // floats per sample in pred/out
    constexpr int WBUF = 64 * ROW;     // 3264 dwords = 13056 B
    constexpr int WOFF1 = 1536;        // dword offset of packed W1 in tail
    constexpr int WOFF2 = 1792;        // dword offset of packed W2

    __shared__ float sbuf[WBUF] __attribute__((aligned(16)));

    const int l = threadIdx.x;         // 0..63, one wave
    float* buf  = sbuf;
    float4* buf4 = reinterpret_cast<float4*>(buf);

    const long long wavebase = (long long)blockIdx.x * 64;

    if (wavebase + 64 <= (long long)B) {
        // ================= coalesced fast path (full wave) =================
        float p[51], a[17], o[51];

        const char* srcB = reinterpret_cast<const char*>(pred + (size_t)wavebase * ROW);
        char* bufB = reinterpret_cast<char*>(buf);

        // ---- phase 1: issue all global traffic ----
        #pragma unroll
        for (int i = 0; i < 12; ++i)
            gload_lds16(srcB + (size_t)(i*64 + l)*16, bufB + i*1024);
        if (l < 48)
            gload_lds16(srcB + (size_t)(768 + l)*16, bufB + 12*1024);

        const float4* asrc4 = reinterpret_cast<const float4*>(anc + (size_t)wavebase * 17);
        float4 ar0 = asrc4[0*64 + l];
        float4 ar1 = asrc4[1*64 + l];
        float4 ar2 = asrc4[2*64 + l];
        float4 ar3 = asrc4[3*64 + l];
        float4 ar4 = asrc4[256 + (l & 15)];   // lanes 16..63 duplicate 0..15

        const float4* gsrc4 = reinterpret_cast<const float4*>(gt + (size_t)(wavebase + l) * 16);
        const float4 gq0 = gsrc4[0], gq1 = gsrc4[1], gq2 = gsrc4[2], gq3 = gsrc4[3];

        // weight fragments for this lane's 8 packed entries (L1/L2-hot)
        float w1a[4], w1b[4], w2a[4], w2b[4];
        #pragma unroll
        for (int q = 0; q < 4; ++q) {
            const int t4 = l + 64*q;
            const int ip = t4 >> 4, j = t4 & 15;
            w1a[q] = gW1[32*ip + j];
            w1b[q] = gW1[32*ip + 16 + j];
            const int jp = t4 >> 5, c = t4 & 31;
            w2a[q] = gW2[64*jp + c];
            w2b[q] = gW2[64*jp + 32 + c];
        }

        __syncthreads();   // drains vmcnt(0): DMA in LDS, anc/gt/weights in regs

        // ---- phase 2: p readback (stride 51, odd -> conflict-free) ----
        #pragma unroll
        for (int j = 0; j < ROW; ++j) p[j] = buf[l*ROW + j];

        __syncthreads();   // p reads drained before region reuse (WAR)

        // ---- phase 3: write anchors [0..1279] + packed weights [1536..2047]
        //      into the freed buffer (no divergence). ----
        buf4[0*64 + l] = ar0;
        buf4[1*64 + l] = ar1;
        buf4[2*64 + l] = ar2;
        buf4[3*64 + l] = ar3;
        buf4[256 + l]  = ar4;
        #pragma unroll
        for (int q = 0; q < 4; ++q) {
            buf[WOFF1 + l + 64*q] = __builtin_bit_cast(float, f2h(w1a[q], w1b[q]));
            buf[WOFF2 + l + 64*q] = __builtin_bit_cast(float, f2h(w2a[q], w2b[q]));
        }

        __syncthreads();   // anc + weight writes visible

        // ---- phase 4: a readback (stride 17, odd -> conflict-free) ----
        #pragma unroll
        for (int j = 0; j < 17; ++j) a[j] = buf[l*17 + j];

        __syncthreads();   // a reads drained before out overwrites region (WAR)

        const float g[16] = {gq0.x,gq0.y,gq0.z,gq0.w, gq1.x,gq1.y,gq1.z,gq1.w,
                             gq2.x,gq2.y,gq2.z,gq2.w, gq3.x,gq3.y,gq3.z,gq3.w};

        const float4* sW1h4 = reinterpret_cast<const float4*>(buf + WOFF1);
        const float4* sW2h4 = reinterpret_cast<const float4*>(buf + WOFF2);
        compute_sample(p, a, g, sW1h4, sW2h4, o);

        // ---- phase 5: transpose out through LDS, coalesced stores ----
        #pragma unroll
        for (int j = 0; j < ROW; ++j) buf[l*ROW + j] = o[j];

        __syncthreads();   // out writes visible

        float4* dst4 = reinterpret_cast<float4*>(out + (size_t)wavebase * ROW);
        #pragma unroll
        for (int i = 0; i < 12; ++i) dst4[i*64 + l] = buf4[i*64 + l];
        if (l < 48) dst4[768 + l] = buf4[768 + l];
    } else {
        // ===== scalar tail path (single partial wave, fp32 weights) =====
        const long long b = wavebase + l;
        if (b < B) {
            float p[51], a[17], g[16], o[51];
            const float* pj = pred + (size_t)b * 51;
            #pragma unroll
            for (int j = 0; j < 51; ++j) p[j] = pj[j];
            const float* ab = anc + (size_t)b * 17;
            #pragma unroll
            for (int j = 0; j < 17; ++j) a[j] = ab[j];
            const float* gb = gt + (size_t)b * 16;
            #pragma unroll
            for (int j = 0; j < 16; ++j) g[j] = gb[j];

            compute_sample_f32(p, a, g, gW1, gW2, o);

            float* ob = out + (size_t)b * 51;
            #pragma unroll
            for (int j = 0; j < 51; ++j) ob[j] = o[j];
        }
    }
}

extern "C" void kernel_launch(void* const* d_in, const int* in_sizes, int n_in,
                              void* d_out, int out_size, void* d_ws, size_t ws_size,
                              hipStream_t stream) {
    const float* pred = (const float*)d_in[0];
    const float* gt   = (const float*)d_in[1];
    const float* anc  = (const float*)d_in[2];
    const float* W1   = (const float*)d_in[3];
    const float* W2   = (const float*)d_in[4];
    float* out = (float*)d_out;

    const int B = in_sizes[0] / 51;
    const int blocks = (B + 63) / 64;
    hipLaunchKernelGGL(projts_kernel, dim3(blocks), dim3(64), 0, stream,
                       pred, gt, anc, W1, W2, out, B);
}